// Round 1
// baseline (14391.403 us; speedup 1.0000x reference)
//
#include <hip/hip_runtime.h>
#include <stdint.h>

// Problem dims (fixed by the reference)
#define TT 512
#define BB 256
#define DD 256
#define HH 512

// Decomposition: 16 batch-groups x 16 H-slices = 256 WGs, 1 per CU.
#define NSLICE 16
#define WSL 32          // h-columns per WG (2 waves x 16)
#define BW 16           // batch rows per group
#define NGROUP 16
#define KS_X 8          // K-chunks of 32 for x part (D=256)
#define KS_H 16         // K-chunks of 32 for h part (H=512)
#define KS_TOT 24
#define NBLK 144        // 2 waves * 3 gates * 24 k-chunks fragment blocks in LDS

typedef __attribute__((ext_vector_type(8))) short short8;
typedef __attribute__((ext_vector_type(4))) float floatx4;

__device__ __forceinline__ short f2bf(float v) {
    union { float f; uint32_t u; } x; x.f = v;
    uint32_t r = (x.u + 0x7fffu + ((x.u >> 16) & 1u)) >> 16;   // RNE
    return (short)r;
}
__device__ __forceinline__ float bf2f(unsigned short s) {
    union { uint32_t u; float f; } x; x.u = ((uint32_t)s) << 16;
    return x.f;
}
__device__ __forceinline__ float sigm(float v) { return 1.0f / (1.0f + __expf(-v)); }

__global__ void init_cnt(unsigned int* cnt) {
    if (threadIdx.x < NGROUP) cnt[threadIdx.x * 64] = 0u;   // 256B-strided counters
}

__global__ __launch_bounds__(128, 1)
void gru_persistent(const float* __restrict__ x,
                    const float* __restrict__ h0,
                    const int*   __restrict__ ep,
                    const float* __restrict__ w_ih,
                    const float* __restrict__ w_hh,
                    const float* __restrict__ b_ih,
                    const float* __restrict__ b_hh,
                    float* __restrict__ out,
                    unsigned int* __restrict__ cnt,
                    unsigned short* __restrict__ exch) {
    // Weights resident as bf16 MFMA B-fragments: block = (wave*3+gate)*24 + ks
    __shared__ short ldsw[NBLK * 512];

    const int tid  = threadIdx.x;
    const int lane = tid & 63;
    const int w    = tid >> 6;            // wave 0..1
    const int b    = blockIdx.x;
    // XCD swizzle: group's 16 WGs land on one XCD (perf only, not correctness)
    const int xcd = b & 7;
    const int idx = b >> 3;               // 0..31
    const int bg  = xcd * 2 + (idx >> 4); // batch group 0..15
    const int sl  = idx & 15;             // H slice 0..15

    // ---- one-time: load + convert + swizzle weights into LDS ----
    for (int u = tid; u < NBLK * 64; u += 128) {
        int blk = u >> 6;
        int l   = u & 63;
        int ww  = blk / 72;
        int rem = blk % 72;
        int g   = rem / 24;
        int ks  = rem % 24;
        int row = sl * WSL + ww * 16 + (l & 15) + g * HH;   // gate row in [0,3H)
        int k0  = ks * 32 + ((l >> 4) * 8);                 // combined K in [0,768)
        const float* src = (k0 < DD) ? (w_ih + (size_t)row * DD + k0)
                                     : (w_hh + (size_t)row * HH + (k0 - DD));
        short8 v;
        #pragma unroll
        for (int j = 0; j < 8; j++) v[j] = f2bf(src[j]);
        *(short8*)&ldsw[(size_t)blk * 512 + l * 8] = v;
    }
    __syncthreads();

    // per-lane constants
    const int cl   = lane & 15;
    const int col  = sl * WSL + w * 16 + cl;   // this lane's output h-column
    const int am   = bg * 16 + cl;             // batch row for A-fragments
    const int rbase = (lane >> 4) * 4;         // epilogue rows
    const int k0a  = (lane >> 4) * 8;
    const float br0 = b_ih[col] + b_hh[col];
    const float bz0 = b_ih[col + HH] + b_hh[col + HH];
    const float bin = b_ih[col + 2 * HH];
    const float bhn = b_hh[col + 2 * HH];

    for (int t = 0; t < TT; t++) {
        floatx4 accI[3], accH[3];
        #pragma unroll
        for (int g = 0; g < 3; g++) {
            accI[g] = (floatx4){0.f, 0.f, 0.f, 0.f};
            accH[g] = (floatx4){0.f, 0.f, 0.f, 0.f};
        }

        // ---- x-side GEMM first: independent of h, hides barrier latency ----
        const float* xrow = x + ((size_t)t * BB + am) * DD;
        #pragma unroll
        for (int ks = 0; ks < KS_X; ks++) {
            int k0 = ks * 32 + k0a;
            short8 a;
            #pragma unroll
            for (int j = 0; j < 8; j++) a[j] = f2bf(xrow[k0 + j]);
            #pragma unroll
            for (int g = 0; g < 3; g++) {
                short8 bf = *(const short8*)&ldsw[(size_t)((w * 3 + g) * KS_TOT + ks) * 512 + lane * 8];
                accI[g] = __builtin_amdgcn_mfma_f32_16x16x32_bf16(a, bf, accI[g], 0, 0, 0);
            }
        }
        const float keepA = (ep[t * BB + am] != 0) ? 0.0f : 1.0f;

        // ---- group barrier: wait until all 16 WGs finished step t-1 ----
        if (t > 0) {
            if (tid == 0) {
                const unsigned int target = (unsigned)(NGROUP * t);
                while (__hip_atomic_load(&cnt[bg * 64], __ATOMIC_RELAXED,
                                         __HIP_MEMORY_SCOPE_AGENT) < target) {
                    __builtin_amdgcn_s_sleep(4);
                }
            }
            __syncthreads();
            __threadfence();   // acquire side: invalidate stale L1/L2 before h loads
        }

        // ---- h-side GEMM ----
        const unsigned short* hbuf = exch + ((size_t)((t & 1) ^ 1)) * BB * HH;
        #pragma unroll
        for (int ks = 0; ks < KS_H; ks++) {
            int k0 = ks * 32 + k0a;
            short8 a;
            if (t == 0) {
                const float* hrow = h0 + (size_t)am * HH;
                #pragma unroll
                for (int j = 0; j < 8; j++) a[j] = f2bf(hrow[k0 + j] * keepA);
            } else {
                a = *(const short8*)(hbuf + (size_t)am * HH + k0);
                if (keepA == 0.0f) {
                    #pragma unroll
                    for (int j = 0; j < 8; j++) a[j] = 0;
                }
            }
            #pragma unroll
            for (int g = 0; g < 3; g++) {
                short8 bf = *(const short8*)&ldsw[(size_t)((w * 3 + g) * KS_TOT + KS_X + ks) * 512 + lane * 8];
                accH[g] = __builtin_amdgcn_mfma_f32_16x16x32_bf16(a, bf, accH[g], 0, 0, 0);
            }
        }

        // ---- epilogue: gates + state update, 4 batch rows per lane ----
        unsigned short* exw = exch + ((size_t)(t & 1)) * BB * HH;
        #pragma unroll
        for (int j = 0; j < 4; j++) {
            const int mo = bg * 16 + rbase + j;
            const float keep = (ep[t * BB + mo] != 0) ? 0.0f : 1.0f;
            float hprev;
            if (t == 0) hprev = h0[(size_t)mo * HH + col] * keep;
            else        hprev = bf2f(hbuf[(size_t)mo * HH + col]) * keep;
            const float r = sigm(accI[0][j] + accH[0][j] + br0);
            const float z = sigm(accI[1][j] + accH[1][j] + bz0);
            const float n = tanhf(accI[2][j] + bin + r * (accH[2][j] + bhn));
            const float hn = (1.0f - z) * n + z * hprev;
            out[((size_t)t * BB + mo) * HH + col] = hn;
            exw[(size_t)mo * HH + col] = (unsigned short)f2bf(hn);
            if (t == TT - 1) out[(size_t)TT * BB * HH + (size_t)mo * HH + col] = hn;
        }

        // ---- release: make exch visible, then arrive ----
        if (t < TT - 1) {
            __threadfence();
            __syncthreads();
            if (tid == 0) {
                __hip_atomic_fetch_add(&cnt[bg * 64], 1u, __ATOMIC_RELEASE,
                                       __HIP_MEMORY_SCOPE_AGENT);
            }
        }
    }
}

extern "C" void kernel_launch(void* const* d_in, const int* in_sizes, int n_in,
                              void* d_out, int out_size, void* d_ws, size_t ws_size,
                              hipStream_t stream) {
    const float* x   = (const float*)d_in[0];
    const float* h0  = (const float*)d_in[1];   // (1,B,H)
    const int*   ep  = (const int*)d_in[2];
    const float* wih = (const float*)d_in[3];
    const float* whh = (const float*)d_in[4];
    const float* bih = (const float*)d_in[5];
    const float* bhh = (const float*)d_in[6];
    float* out = (float*)d_out;

    unsigned int*   cnt  = (unsigned int*)d_ws;                       // 16 counters, 256B stride
    unsigned short* exch = (unsigned short*)((char*)d_ws + 16384);    // 2 x B x H bf16 ping-pong

    hipLaunchKernelGGL(init_cnt, dim3(1), dim3(64), 0, stream, cnt);
    hipLaunchKernelGGL(gru_persistent, dim3(256), dim3(128), 0, stream,
                       x, h0, ep, wih, whh, bih, bhh, out, cnt, exch);
}

// Round 2
// 3287.795 us; speedup vs baseline: 4.3772x; 4.3772x over previous
//
#include <hip/hip_runtime.h>
#include <stdint.h>

// Problem dims (fixed by the reference)
#define TT 512
#define BB 256
#define DD 256
#define HH 512

// Decomposition: 16 batch-groups x 16 H-slices = 256 WGs, 1 per CU.
#define WSL 32          // h-columns per WG (2 waves x 16)
#define NGROUP 16
#define KS_X 8          // K-chunks of 32 for x part (D=256)
#define KS_H 16         // K-chunks of 32 for h part (H=512)
#define KS_TOT 24
#define NBLK 144        // 2 waves * 3 gates * 24 k-chunks fragment blocks in LDS

typedef __attribute__((ext_vector_type(8))) short short8;
typedef __attribute__((ext_vector_type(4))) float floatx4;

__device__ __forceinline__ short f2bf(float v) {
    union { float f; uint32_t u; } x; x.f = v;
    uint32_t r = (x.u + 0x7fffu + ((x.u >> 16) & 1u)) >> 16;   // RNE
    return (short)r;
}
__device__ __forceinline__ float bf2f(unsigned int s) {
    union { uint32_t u; float f; } x; x.u = (s & 0xffffu) << 16;
    return x.f;
}
__device__ __forceinline__ float sigm(float v) { return 1.0f / (1.0f + __expf(-v)); }

__global__ void init_flags(unsigned int* f) { f[threadIdx.x * 32] = 0u; }   // 256 flags, 128B apart

__global__ __launch_bounds__(128, 1)
void gru_persistent(const float* __restrict__ x,
                    const float* __restrict__ h0,
                    const int*   __restrict__ ep,
                    const float* __restrict__ w_ih,
                    const float* __restrict__ w_hh,
                    const float* __restrict__ b_ih,
                    const float* __restrict__ b_hh,
                    float* __restrict__ out,
                    unsigned int* __restrict__ flags,
                    unsigned short* __restrict__ exch) {
    // Weights resident as bf16 MFMA B-fragments: block = (wave*3+gate)*24 + ks
    __shared__ short ldsw[NBLK * 512];

    const int tid  = threadIdx.x;
    const int lane = tid & 63;
    const int w    = tid >> 6;            // wave 0..1
    const int b    = blockIdx.x;
    // XCD swizzle: group's 16 WGs land on one XCD (perf only, not correctness)
    const int xcd = b & 7;
    const int idx = b >> 3;               // 0..31
    const int bg  = xcd * 2 + (idx >> 4); // batch group 0..15
    const int sl  = idx & 15;             // H slice 0..15

    // ---- one-time: load + convert + swizzle weights into LDS ----
    for (int u = tid; u < NBLK * 64; u += 128) {
        int blk = u >> 6;
        int l   = u & 63;
        int ww  = blk / 72;
        int rem = blk % 72;
        int g   = rem / 24;
        int ks  = rem % 24;
        int row = sl * WSL + ww * 16 + (l & 15) + g * HH;   // gate row in [0,3H)
        int k0  = ks * 32 + ((l >> 4) * 8);                 // combined K in [0,768)
        const float* src = (k0 < DD) ? (w_ih + (size_t)row * DD + k0)
                                     : (w_hh + (size_t)row * HH + (k0 - DD));
        short8 v;
        #pragma unroll
        for (int j = 0; j < 8; j++) v[j] = f2bf(src[j]);
        *(short8*)&ldsw[(size_t)blk * 512 + l * 8] = v;
    }
    __syncthreads();

    // per-lane constants
    const int cl   = lane & 15;
    const int col  = sl * WSL + w * 16 + cl;   // this lane's output h-column
    const int am   = bg * 16 + cl;             // batch row for A-fragments
    const int rbase = (lane >> 4) * 4;         // epilogue rows
    const int k0a  = (lane >> 4) * 8;
    const float br0 = b_ih[col] + b_hh[col];
    const float bz0 = b_ih[col + HH] + b_hh[col + HH];
    const float bin = b_ih[col + 2 * HH];
    const float bhn = b_hh[col + 2 * HH];

    for (int t = 0; t < TT; t++) {
        floatx4 accI[3], accH[3];
        #pragma unroll
        for (int g = 0; g < 3; g++) {
            accI[g] = (floatx4){0.f, 0.f, 0.f, 0.f};
            accH[g] = (floatx4){0.f, 0.f, 0.f, 0.f};
        }

        // ---- x-side GEMM first: independent of h, hides sync latency ----
        const float* xrow = x + ((size_t)t * BB + am) * DD;
        #pragma unroll
        for (int ks = 0; ks < KS_X; ks++) {
            int k0 = ks * 32 + k0a;
            short8 a;
            #pragma unroll
            for (int j = 0; j < 8; j++) a[j] = f2bf(xrow[k0 + j]);
            #pragma unroll
            for (int g = 0; g < 3; g++) {
                short8 bf = *(const short8*)&ldsw[(size_t)((w * 3 + g) * KS_TOT + ks) * 512 + lane * 8];
                accI[g] = __builtin_amdgcn_mfma_f32_16x16x32_bf16(a, bf, accI[g], 0, 0, 0);
            }
        }
        const float keepA = (ep[t * BB + am] != 0) ? 0.0f : 1.0f;

        // ---- acquire: 16 lanes poll the 16 producer flags in parallel ----
        if (t > 0) {
            if (w == 0) {
                const unsigned int target = (unsigned int)t;
                for (;;) {
                    unsigned int v = 0xFFFFFFFFu;
                    if (lane < NGROUP)
                        v = __hip_atomic_load(&flags[(bg * NGROUP + lane) * 32],
                                              __ATOMIC_RELAXED, __HIP_MEMORY_SCOPE_AGENT);
                    if (__all(v >= target)) break;
                    __builtin_amdgcn_s_sleep(1);
                }
            }
            __syncthreads();
        }

        // ---- h-side A-fragments + h_prev: coherent (sc0 sc1) LLC loads ----
        const unsigned short* hbuf = exch + ((size_t)((t & 1) ^ 1)) * BB * HH;
        short8 a[KS_H];
        unsigned int hp[4];
        if (t == 0) {
            const float* hrow = h0 + (size_t)am * HH;
            #pragma unroll
            for (int ks = 0; ks < KS_H; ks++) {
                int k0 = ks * 32 + k0a;
                #pragma unroll
                for (int j = 0; j < 8; j++) a[ks][j] = f2bf(hrow[k0 + j] * keepA);
            }
        } else {
            const unsigned short* hb = hbuf + (size_t)am * HH + k0a;
            #pragma unroll
            for (int ks = 0; ks < KS_H; ks++) {
                asm volatile("global_load_dwordx4 %0, %1, off sc0 sc1"
                             : "=&v"(a[ks]) : "v"(hb + ks * 32) : "memory");
            }
            #pragma unroll
            for (int j = 0; j < 4; j++) {
                const unsigned short* hq = hbuf + (size_t)(bg * 16 + rbase + j) * HH + col;
                asm volatile("global_load_ushort %0, %1, off sc0 sc1"
                             : "=&v"(hp[j]) : "v"(hq) : "memory");
            }
            asm volatile("s_waitcnt vmcnt(0)" ::: "memory");
            __builtin_amdgcn_sched_barrier(0);
            if (keepA == 0.0f) {
                #pragma unroll
                for (int ks = 0; ks < KS_H; ks++) a[ks] = (short8)0;
            }
        }

        // ---- h-side GEMM ----
        #pragma unroll
        for (int ks = 0; ks < KS_H; ks++) {
            #pragma unroll
            for (int g = 0; g < 3; g++) {
                short8 bf = *(const short8*)&ldsw[(size_t)((w * 3 + g) * KS_TOT + KS_X + ks) * 512 + lane * 8];
                accH[g] = __builtin_amdgcn_mfma_f32_16x16x32_bf16(a[ks], bf, accH[g], 0, 0, 0);
            }
        }

        // ---- epilogue: gates + state update; exch stores go out first ----
        unsigned short* exw = exch + ((size_t)(t & 1)) * BB * HH;
        float hnv[4];
        #pragma unroll
        for (int j = 0; j < 4; j++) {
            const int mo = bg * 16 + rbase + j;
            const float keep = (ep[t * BB + mo] != 0) ? 0.0f : 1.0f;
            float hprev;
            if (t == 0) hprev = h0[(size_t)mo * HH + col] * keep;
            else        hprev = bf2f(hp[j]) * keep;
            const float r = sigm(accI[0][j] + accH[0][j] + br0);
            const float z = sigm(accI[1][j] + accH[1][j] + bz0);
            const float n = tanhf(accI[2][j] + bin + r * (accH[2][j] + bhn));
            hnv[j] = (1.0f - z) * n + z * hprev;
            if (t < TT - 1) {
                unsigned short* pw = exw + (size_t)mo * HH + col;
                unsigned int bits = (unsigned int)(unsigned short)f2bf(hnv[j]);
                asm volatile("global_store_short %0, %1, off sc0 sc1"
                             :: "v"(pw), "v"(bits) : "memory");
            }
        }

        // ---- release: drain exch stores, then per-WG flag (no RMW) ----
        if (t < TT - 1) {
            asm volatile("s_waitcnt vmcnt(0)" ::: "memory");
            __syncthreads();
            if (tid == 0) {
                __hip_atomic_store(&flags[(bg * NGROUP + sl) * 32], (unsigned int)(t + 1),
                                   __ATOMIC_RELAXED, __HIP_MEMORY_SCOPE_AGENT);
            }
        }

        // ---- out stores: plain cached, off the critical path ----
        #pragma unroll
        for (int j = 0; j < 4; j++) {
            const int mo = bg * 16 + rbase + j;
            out[((size_t)t * BB + mo) * HH + col] = hnv[j];
            if (t == TT - 1) out[(size_t)TT * BB * HH + (size_t)mo * HH + col] = hnv[j];
        }
    }
}

extern "C" void kernel_launch(void* const* d_in, const int* in_sizes, int n_in,
                              void* d_out, int out_size, void* d_ws, size_t ws_size,
                              hipStream_t stream) {
    const float* x   = (const float*)d_in[0];
    const float* h0  = (const float*)d_in[1];   // (1,B,H)
    const int*   ep  = (const int*)d_in[2];
    const float* wih = (const float*)d_in[3];
    const float* whh = (const float*)d_in[4];
    const float* bih = (const float*)d_in[5];
    const float* bhh = (const float*)d_in[6];
    float* out = (float*)d_out;

    unsigned int*   flags = (unsigned int*)d_ws;                      // 256 flags, 128B stride
    unsigned short* exch  = (unsigned short*)((char*)d_ws + 32768);   // 2 x B x H bf16 ping-pong

    hipLaunchKernelGGL(init_flags, dim3(1), dim3(256), 0, stream, flags);
    hipLaunchKernelGGL(gru_persistent, dim3(256), dim3(128), 0, stream,
                       x, h0, ep, wih, whh, bih, bhh, out, flags, exch);
}